// Round 1
// baseline (495.541 us; speedup 1.0000x reference)
//
#include <hip/hip_runtime.h>
#include <hip/hip_bf16.h>

// HadamardTrustQuantizer forward:
//   out = H128( clip(round(H128(x)/step), -7, 7) * step ), step = ALPHA*rms/7
// Forward value of the straight-through estimator is exactly xq (mask cancels).
//
// Implementation: unnormalized fast Walsh-Hadamard (Sylvester) butterflies,
// one 4096-elem row per wave (64 fp32 per lane, registers only, no LDS).
// Scales folded: std clamp at 1e-8*sqrt(128); single exact *1/128 at store.

#define HTQ_ALPHA 2.5139f
#define HTQ_QMAX  7.0f

__global__ __launch_bounds__(256) void htq_kernel(const float* __restrict__ x,
                                                  float* __restrict__ out) {
    const int gid  = blockIdx.x * 256 + threadIdx.x;
    const int row  = gid >> 6;            // one 4096-elem row per wave
    const int lane = threadIdx.x & 63;

    const size_t base = (size_t)row * 4096 + (size_t)lane * 64;

    float v[64];
    float4* v4 = reinterpret_cast<float4*>(v);
    const float4* g4 = reinterpret_cast<const float4*>(x + base);
#pragma unroll
    for (int q = 0; q < 16; ++q) v4[q] = g4[q];

    // ---- FWHT #1 (unnormalized). In-register strides 1..32 ----
#pragma unroll
    for (int s = 1; s < 64; s <<= 1) {
#pragma unroll
        for (int i = 0; i < 64; ++i) {
            if ((i & s) == 0) {
                float a = v[i], b = v[i + s];
                v[i]     = a + b;
                v[i + s] = a - b;
            }
        }
    }
    // stride-64 stage: lanes 2b / 2b+1 hold halves of block b. DPP-friendly xor-1.
    const float sgn = (lane & 1) ? -1.0f : 1.0f;
#pragma unroll
    for (int i = 0; i < 64; ++i) {
        float p = __shfl_xor(v[i], 1, 64);
        v[i] = fmaf(sgn, v[i], p);   // even lane: v+p ; odd lane: p-v (exact)
    }

    // ---- row RMS (rotation preserves layout-agnostic sum of squares) ----
    float ss = 0.0f;
#pragma unroll
    for (int i = 0; i < 64; ++i) ss = fmaf(v[i], v[i], ss);
#pragma unroll
    for (int m = 1; m < 64; m <<= 1) ss += __shfl_xor(ss, m, 64);

    // y = sqrt(128)*x_h  =>  std_y = sqrt(128)*std_ref
    float std_y = sqrtf(ss * (1.0f / 4096.0f));
    std_y = fmaxf(std_y, 1.1313708499e-7f);          // 1e-8 * sqrt(128)
    const float step = (HTQ_ALPHA * std_y) / HTQ_QMAX;

    // ---- quantize (IEEE div to track np's x_h/step through round()) ----
#pragma unroll
    for (int i = 0; i < 64; ++i) {
        float r = rintf(v[i] / step);                // round-half-even, like np
        r = fminf(fmaxf(r, -HTQ_QMAX), HTQ_QMAX);
        v[i] = r * step;
    }

    // ---- FWHT #2 ----
#pragma unroll
    for (int s = 1; s < 64; s <<= 1) {
#pragma unroll
        for (int i = 0; i < 64; ++i) {
            if ((i & s) == 0) {
                float a = v[i], b = v[i + s];
                v[i]     = a + b;
                v[i + s] = a - b;
            }
        }
    }
#pragma unroll
    for (int i = 0; i < 64; ++i) {
        float p = __shfl_xor(v[i], 1, 64);
        v[i] = fmaf(sgn, v[i], p);
    }

    // ---- store with single exact scale 1/128 (power of two) ----
    float4* o4 = reinterpret_cast<float4*>(out + base);
#pragma unroll
    for (int q = 0; q < 16; ++q) {
        float4 t = v4[q];
        t.x *= 0.0078125f; t.y *= 0.0078125f; t.z *= 0.0078125f; t.w *= 0.0078125f;
        o4[q] = t;
    }
}

extern "C" void kernel_launch(void* const* d_in, const int* in_sizes, int n_in,
                              void* d_out, int out_size, void* d_ws, size_t ws_size,
                              hipStream_t stream) {
    const float* x = (const float*)d_in[0];
    // d_in[1] is H (128x128): deterministic Sylvester Hadamard/sqrt(128) — FWHT
    // implements it directly, so it is unused.
    float* out = (float*)d_out;

    const int n    = in_sizes[0];        // 4*4096*4096
    const int rows = n / 4096;           // 16384
    const int waves_total = rows;        // one wave per row
    const int blocks = (waves_total * 64) / 256;

    hipLaunchKernelGGL(htq_kernel, dim3(blocks), dim3(256), 0, stream, x, out);
}

// Round 2
// 440.331 us; speedup vs baseline: 1.1254x; 1.1254x over previous
//
#include <hip/hip_runtime.h>
#include <hip/hip_bf16.h>

// HadamardTrustQuantizer forward:
//   out = H128( clip(round(H128(x)/step), -7, 7) * step ), step = ALPHA*rms/7
// STE forward value is exactly xq (trust mask cancels in the forward pass).
//
// R2: fully-coalesced layout. Lane l owns, for each of 16 segments t,
// the float4 at row*4096 + t*256 + l*4  (register i = t*4+m  <->  element
// e = t*256 + l*4 + m). Within a 128-block: w = (l&31)*4 + m, so FWHT
// strides 1,2 are in-register; strides 4..64 are lane-xor 1,2,4,8,16.
// xor1/xor2 -> DPP quad_perm, xor8 -> DPP row_ror:8 (VALU-rate);
// xor4/xor16 -> ds_swizzle. No LDS arrays, no barriers.

#define HTQ_ALPHA 2.5139f
#define HTQ_QMAX  7.0f

template <int CTRL>
__device__ __forceinline__ float dpp_perm(float f) {
    int r = __builtin_amdgcn_update_dpp(__float_as_int(f), __float_as_int(f),
                                        CTRL, 0xF, 0xF, true);
    return __int_as_float(r);
}

template <int MASK>
__device__ __forceinline__ float swz_xor(float f) {
    int r = __builtin_amdgcn_ds_swizzle(__float_as_int(f), (MASK << 10) | 0x1F);
    return __int_as_float(r);
}

// one cross-lane butterfly stage: v = (lane&bit) ? partner - v : v + partner
#define CROSS_STAGE(GETP, BIT)                                   \
    {                                                            \
        const float sg = (lane & (BIT)) ? -1.0f : 1.0f;          \
        _Pragma("unroll")                                        \
        for (int i = 0; i < 64; ++i) {                           \
            float p = GETP(v[i]);                                \
            v[i] = fmaf(sg, v[i], p);                            \
        }                                                        \
    }

__device__ __forceinline__ void fwht128(float v[64], int lane) {
    // strides 1,2: inside each float4 group of registers
#pragma unroll
    for (int g = 0; g < 16; ++g) {
        float a0 = v[4 * g], a1 = v[4 * g + 1], a2 = v[4 * g + 2], a3 = v[4 * g + 3];
        float t0 = a0 + a1, t1 = a0 - a1, t2 = a2 + a3, t3 = a2 - a3;
        v[4 * g]     = t0 + t2;
        v[4 * g + 1] = t1 + t3;
        v[4 * g + 2] = t0 - t2;
        v[4 * g + 3] = t1 - t3;
    }
    // strides 4,8,16,32,64 -> lane xor 1,2,4,8,16
    CROSS_STAGE(dpp_perm<0xB1>, 1)    // quad_perm [1,0,3,2]
    CROSS_STAGE(dpp_perm<0x4E>, 2)    // quad_perm [2,3,0,1]
    CROSS_STAGE(swz_xor<4>, 4)        // ds_swizzle xor-4
    CROSS_STAGE(dpp_perm<0x128>, 8)   // row_ror:8 == xor 8 within 16-lane row
    CROSS_STAGE(swz_xor<16>, 16)      // ds_swizzle xor-16
}

__global__ __launch_bounds__(256) void htq_kernel(const float* __restrict__ x,
                                                  float* __restrict__ out) {
    const int gid  = blockIdx.x * 256 + threadIdx.x;
    const int row  = gid >> 6;
    const int lane = threadIdx.x & 63;

    const size_t base = (size_t)row * 4096 + (size_t)lane * 4;

    float v[64];
    float4* v4 = reinterpret_cast<float4*>(v);
    const float4* g4 = reinterpret_cast<const float4*>(x + base);
#pragma unroll
    for (int t = 0; t < 16; ++t) v4[t] = g4[(size_t)t * 64];  // +t*256 floats, unit-stride per wave

    fwht128(v, lane);   // y = sqrt(128) * x_h  (unnormalized)

    // row RMS over all 4096 elements (whole wave holds one row)
    float ss = 0.0f;
#pragma unroll
    for (int i = 0; i < 64; ++i) ss = fmaf(v[i], v[i], ss);
#pragma unroll
    for (int m = 1; m < 64; m <<= 1) ss += __shfl_xor(ss, m, 64);

    float std_y = sqrtf(ss * (1.0f / 4096.0f));       // = sqrt(128)*std_ref
    std_y = fmaxf(std_y, 1.1313708499e-7f);           // 1e-8 * sqrt(128)
    const float step = (HTQ_ALPHA * std_y) / HTQ_QMAX;

    // quantize (exact IEEE div to track np's x_h/step through rint)
#pragma unroll
    for (int i = 0; i < 64; ++i) {
        float r = rintf(v[i] / step);
        r = fminf(fmaxf(r, -HTQ_QMAX), HTQ_QMAX);
        v[i] = r * step;
    }

    fwht128(v, lane);   // back-rotate (unnormalized)

    // store with single exact scale 1/128 (power of two), unit-stride per wave
    float4* o4 = reinterpret_cast<float4*>(out + base);
#pragma unroll
    for (int t = 0; t < 16; ++t) {
        float4 w = v4[t];
        w.x *= 0.0078125f; w.y *= 0.0078125f; w.z *= 0.0078125f; w.w *= 0.0078125f;
        o4[(size_t)t * 64] = w;
    }
}

extern "C" void kernel_launch(void* const* d_in, const int* in_sizes, int n_in,
                              void* d_out, int out_size, void* d_ws, size_t ws_size,
                              hipStream_t stream) {
    const float* x = (const float*)d_in[0];
    float* out = (float*)d_out;

    const int n    = in_sizes[0];     // 4*4096*4096
    const int rows = n / 4096;        // one wave per 4096-elem row
    const int blocks = (rows * 64) / 256;

    hipLaunchKernelGGL(htq_kernel, dim3(blocks), dim3(256), 0, stream, x, out);
}